// Round 1
// baseline (5982.859 us; speedup 1.0000x reference)
//
#include <hip/hip_runtime.h>
#include <hip/hip_bf16.h>

#define N_NODES_C 100000
#define FEATS 128
#define MT 64
#define KC 32

// HW fp32 global atomic (global_atomic_add_f32), avoids CAS loop
__device__ __forceinline__ void atomic_add_f32(float* p, float v) {
#if __has_builtin(__builtin_amdgcn_is_shared)
    unsafeAtomicAdd(p, v);
#else
    atomicAdd(p, v);
#endif
}

__global__ void deg_kernel(const int* __restrict__ dst, float* __restrict__ deg, int nE) {
    int i = blockIdx.x * blockDim.x + threadIdx.x;
    if (i < nE) atomic_add_f32(&deg[dst[i]], 1.0f);
}

// 32 threads per edge; each thread moves one float4 (h[src] -> agg[dst])
__global__ void scatter_kernel(const float* __restrict__ h,
                               const int* __restrict__ src,
                               const int* __restrict__ dst,
                               float* __restrict__ agg, int nE) {
    int gid = blockIdx.x * blockDim.x + threadIdx.x;
    int e = gid >> 5;
    if (e >= nE) return;
    int lane = gid & 31;
    int s = src[e];
    int d = dst[e];
    const float4 v = *(const float4*)(h + (size_t)s * FEATS + lane * 4);
    float* o = agg + (size_t)d * FEATS + lane * 4;
    atomic_add_f32(o + 0, v.x);
    atomic_add_f32(o + 1, v.y);
    atomic_add_f32(o + 2, v.z);
    atomic_add_f32(o + 3, v.w);
}

// out[n,:] = H[n,:] @ Ws + (AGG[n,:]/max(deg,1)) @ Wn + b  (+ optional leaky-relu 0.2)
// Tile: 64 nodes x 128 cols per block, K chunks of 32. 256 threads.
// Thread (tx,ty): cols 4*tx..4*tx+3, rows ty*8..ty*8+7 -> 32 fp32 accumulators.
__global__ __launch_bounds__(256) void sage_gemm(
    const float* __restrict__ H,
    const float* __restrict__ AGG,
    const float* __restrict__ DEG,
    const float* __restrict__ Ws,
    const float* __restrict__ Wn,
    const float* __restrict__ bias,
    float* __restrict__ OUT,
    int nNodes, int applyLrelu)
{
    __shared__ float sH[MT][KC + 1];
    __shared__ float sM[MT][KC + 1];
    __shared__ float sW[KC][FEATS];
    __shared__ float sV[KC][FEATS];

    const int tid = threadIdx.x;
    const int tx = tid & 31;
    const int ty = tid >> 5;
    const int rowBase = blockIdx.x * MT;

    float4 acc[8];
#pragma unroll
    for (int r = 0; r < 8; ++r) acc[r] = make_float4(0.f, 0.f, 0.f, 0.f);

    for (int kc = 0; kc < FEATS; kc += KC) {
        // A tiles: 64 rows x 32 cols = 512 float4 per matrix, 2 per thread
#pragma unroll
        for (int i = 0; i < 2; ++i) {
            int idx = tid + i * 256;      // 0..511
            int row = idx >> 3;           // 0..63
            int c4  = idx & 7;            // 0..7
            int gr  = rowBase + row;
            float4 hv = make_float4(0.f, 0.f, 0.f, 0.f);
            float4 mv = make_float4(0.f, 0.f, 0.f, 0.f);
            if (gr < nNodes) {
                hv = *(const float4*)(H + (size_t)gr * FEATS + kc + c4 * 4);
                float4 av = *(const float4*)(AGG + (size_t)gr * FEATS + kc + c4 * 4);
                float inv = 1.0f / fmaxf(DEG[gr], 1.0f);
                mv = make_float4(av.x * inv, av.y * inv, av.z * inv, av.w * inv);
            }
            sH[row][c4 * 4 + 0] = hv.x;
            sH[row][c4 * 4 + 1] = hv.y;
            sH[row][c4 * 4 + 2] = hv.z;
            sH[row][c4 * 4 + 3] = hv.w;
            sM[row][c4 * 4 + 0] = mv.x;
            sM[row][c4 * 4 + 1] = mv.y;
            sM[row][c4 * 4 + 2] = mv.z;
            sM[row][c4 * 4 + 3] = mv.w;
        }
        // W tiles: 32 rows x 128 cols = 1024 float4 per matrix, 4 per thread
#pragma unroll
        for (int i = 0; i < 4; ++i) {
            int idx = tid + i * 256;      // 0..1023
            int row = idx >> 5;           // 0..31
            int c4  = idx & 31;           // 0..31
            *(float4*)&sW[row][c4 * 4] = *(const float4*)(Ws + (size_t)(kc + row) * FEATS + c4 * 4);
            *(float4*)&sV[row][c4 * 4] = *(const float4*)(Wn + (size_t)(kc + row) * FEATS + c4 * 4);
        }
        __syncthreads();

#pragma unroll
        for (int k = 0; k < KC; ++k) {
            float4 ws = *(const float4*)&sW[k][tx * 4];
            float4 wn = *(const float4*)&sV[k][tx * 4];
#pragma unroll
            for (int r = 0; r < 8; ++r) {
                float ah = sH[ty * 8 + r][k];
                float am = sM[ty * 8 + r][k];
                acc[r].x += ah * ws.x + am * wn.x;
                acc[r].y += ah * ws.y + am * wn.y;
                acc[r].z += ah * ws.z + am * wn.z;
                acc[r].w += ah * ws.w + am * wn.w;
            }
        }
        __syncthreads();
    }

    float4 bv = *(const float4*)(bias + tx * 4);
#pragma unroll
    for (int r = 0; r < 8; ++r) {
        int gr = rowBase + ty * 8 + r;
        if (gr >= nNodes) continue;
        float4 v;
        v.x = acc[r].x + bv.x;
        v.y = acc[r].y + bv.y;
        v.z = acc[r].z + bv.z;
        v.w = acc[r].w + bv.w;
        if (applyLrelu) {
            v.x = v.x > 0.f ? v.x : 0.2f * v.x;
            v.y = v.y > 0.f ? v.y : 0.2f * v.y;
            v.z = v.z > 0.f ? v.z : 0.2f * v.z;
            v.w = v.w > 0.f ? v.w : 0.2f * v.w;
        }
        *(float4*)(OUT + (size_t)gr * FEATS + tx * 4) = v;
    }
}

extern "C" void kernel_launch(void* const* d_in, const int* in_sizes, int n_in,
                              void* d_out, int out_size, void* d_ws, size_t ws_size,
                              hipStream_t stream) {
    const float* emb = (const float*)d_in[0];
    const float* W1s = (const float*)d_in[1];
    const float* W1n = (const float*)d_in[2];
    const float* b1  = (const float*)d_in[3];
    const float* W2s = (const float*)d_in[4];
    const float* W2n = (const float*)d_in[5];
    const float* b2  = (const float*)d_in[6];
    const int*   edg = (const int*)d_in[7];

    const int nE = in_sizes[7] / 2;
    const int* src = edg;
    const int* dst = edg + nE;

    const size_t aggBytes = (size_t)N_NODES_C * FEATS * sizeof(float);
    char* ws = (char*)d_ws;
    float* deg = (float*)ws;                                   // 400 KB used, 512 KB reserved
    float* agg = (float*)(ws + (512 << 10));                   // 51.2 MB
    float* h1  = (float*)(ws + (512 << 10) + aggBytes);        // 51.2 MB
    float* out = (float*)d_out;

    hipMemsetAsync(deg, 0, N_NODES_C * sizeof(float), stream);
    hipMemsetAsync(agg, 0, aggBytes, stream);

    deg_kernel<<<(nE + 255) / 256, 256, 0, stream>>>(dst, deg, nE);

    const int scatterBlocks = (int)(((size_t)nE * 32 + 255) / 256);
    scatter_kernel<<<scatterBlocks, 256, 0, stream>>>(emb, src, dst, agg, nE);

    const int gemmBlocks = (N_NODES_C + MT - 1) / MT;
    sage_gemm<<<gemmBlocks, 256, 0, stream>>>(emb, agg, deg, W1s, W1n, b1, h1, N_NODES_C, 1);

    hipMemsetAsync(agg, 0, aggBytes, stream);
    scatter_kernel<<<scatterBlocks, 256, 0, stream>>>(h1, src, dst, agg, nE);
    sage_gemm<<<gemmBlocks, 256, 0, stream>>>(h1, agg, deg, W2s, W2n, b2, out, N_NODES_C, 0);
}

// Round 2
// 958.922 us; speedup vs baseline: 6.2392x; 6.2392x over previous
//
#include <hip/hip_runtime.h>
#include <hip/hip_bf16.h>

#define N_NODES_C 100000
#define FEATS 128
#define MT 64
#define KC 32
#define SCAN_CHUNK 1024   // 256 threads x 4 elements

// ---------------- CSR build ----------------

__global__ void hist_kernel(const int* __restrict__ dst, int* __restrict__ cnt, int nE) {
    int i = blockIdx.x * blockDim.x + threadIdx.x;
    if (i < nE) atomicAdd(&cnt[dst[i]], 1);
}

// Exclusive scan phase A: per-block scan of 1024-element chunks.
// Scans domain of n = N_NODES_C+1 elements where cnt[i>=N_NODES_C] := 0,
// producing off[0..n) (partial, needs block-offset add) and partials[b].
__global__ __launch_bounds__(256) void scanA_kernel(const int* __restrict__ cnt,
                                                    int* __restrict__ off,
                                                    int* __restrict__ partials, int n) {
    __shared__ int ss[256];
    const int tid = threadIdx.x;
    const int base = blockIdx.x * SCAN_CHUNK;
    const int idx0 = base + tid * 4;
    int c[4];
#pragma unroll
    for (int i = 0; i < 4; ++i) {
        int gi = idx0 + i;
        c[i] = (gi < N_NODES_C) ? cnt[gi] : 0;
    }
    int s0 = c[0] + c[1] + c[2] + c[3];
    ss[tid] = s0;
    __syncthreads();
    // Hillis-Steele inclusive scan over 256 thread sums
    for (int d = 1; d < 256; d <<= 1) {
        int t = (tid >= d) ? ss[tid - d] : 0;
        __syncthreads();
        ss[tid] += t;
        __syncthreads();
    }
    if (tid == 255) partials[blockIdx.x] = ss[255];
    int ex = ss[tid] - s0;  // exclusive prefix of this thread within block
    int run = 0;
#pragma unroll
    for (int i = 0; i < 4; ++i) {
        int gi = idx0 + i;
        if (gi < n) off[gi] = ex + run;
        run += c[i];
    }
}

// Phase B: single-block exclusive scan of partials (nP <= 128)
__global__ __launch_bounds__(128) void scanB_kernel(int* __restrict__ partials, int nP) {
    __shared__ int sp[128];
    const int tid = threadIdx.x;
    int orig = (tid < nP) ? partials[tid] : 0;
    sp[tid] = orig;
    __syncthreads();
    for (int d = 1; d < 128; d <<= 1) {
        int t = (tid >= d) ? sp[tid - d] : 0;
        __syncthreads();
        sp[tid] += t;
        __syncthreads();
    }
    if (tid < nP) partials[tid] = sp[tid] - orig;  // exclusive
}

// Phase C: add block offsets
__global__ __launch_bounds__(256) void scanC_kernel(int* __restrict__ off,
                                                    const int* __restrict__ partials, int n) {
    const int base = blockIdx.x * SCAN_CHUNK;
    const int add = partials[blockIdx.x];
    const int idx0 = base + threadIdx.x * 4;
#pragma unroll
    for (int i = 0; i < 4; ++i) {
        int gi = idx0 + i;
        if (gi < n) off[gi] += add;
    }
}

__global__ void copy_kernel(const int* __restrict__ a, int* __restrict__ b, int n) {
    int i = blockIdx.x * blockDim.x + threadIdx.x;
    if (i < n) b[i] = a[i];
}

__global__ void fill_kernel(const int* __restrict__ src, const int* __restrict__ dst,
                            int* __restrict__ cursor, int* __restrict__ csr, int nE) {
    int e = blockIdx.x * blockDim.x + threadIdx.x;
    if (e < nE) {
        int d = dst[e];
        int pos = atomicAdd(&cursor[d], 1);
        csr[pos] = src[e];
    }
}

// ---------------- Gather (mean aggregation, no atomics) ----------------
// 2 nodes per 256-thread block; 128 threads per node, one feature col each.
__global__ __launch_bounds__(256) void gather_mean(const float* __restrict__ h,
                                                   const int* __restrict__ csr,
                                                   const int* __restrict__ off,
                                                   float* __restrict__ mean, int nNodes) {
    const int node = blockIdx.x * 2 + (threadIdx.x >> 7);
    const int col = threadIdx.x & 127;
    if (node >= nNodes) return;
    const int start = off[node];
    const int end = off[node + 1];
    float acc = 0.f;
    int e0 = start;
    // unrolled-by-8 chunks: independent loads for memory-level parallelism
    for (; e0 + 8 <= end; e0 += 8) {
        int s[8];
#pragma unroll
        for (int j = 0; j < 8; ++j) s[j] = csr[e0 + j];
        float v[8];
#pragma unroll
        for (int j = 0; j < 8; ++j) v[j] = h[(size_t)s[j] * FEATS + col];
#pragma unroll
        for (int j = 0; j < 8; ++j) acc += v[j];
    }
    for (; e0 < end; ++e0) acc += h[(size_t)csr[e0] * FEATS + col];
    const int deg = end - start;
    const float invd = (deg > 0) ? (1.f / (float)deg) : 0.f;
    mean[(size_t)node * FEATS + col] = acc * invd;
}

// ---------------- Fused SAGE GEMM ----------------
// out[n,:] = H[n,:] @ Ws + MEAN[n,:] @ Wn + b  (+ optional leaky-relu 0.2)
__global__ __launch_bounds__(256) void sage_gemm(
    const float* __restrict__ H,
    const float* __restrict__ MEAN,
    const float* __restrict__ Ws,
    const float* __restrict__ Wn,
    const float* __restrict__ bias,
    float* __restrict__ OUT,
    int nNodes, int applyLrelu)
{
    __shared__ float sH[MT][KC + 1];
    __shared__ float sM[MT][KC + 1];
    __shared__ float sW[KC][FEATS];
    __shared__ float sV[KC][FEATS];

    const int tid = threadIdx.x;
    const int tx = tid & 31;
    const int ty = tid >> 5;
    const int rowBase = blockIdx.x * MT;

    float4 acc[8];
#pragma unroll
    for (int r = 0; r < 8; ++r) acc[r] = make_float4(0.f, 0.f, 0.f, 0.f);

    for (int kc = 0; kc < FEATS; kc += KC) {
#pragma unroll
        for (int i = 0; i < 2; ++i) {
            int idx = tid + i * 256;
            int row = idx >> 3;
            int c4  = idx & 7;
            int gr  = rowBase + row;
            float4 hv = make_float4(0.f, 0.f, 0.f, 0.f);
            float4 mv = make_float4(0.f, 0.f, 0.f, 0.f);
            if (gr < nNodes) {
                hv = *(const float4*)(H + (size_t)gr * FEATS + kc + c4 * 4);
                mv = *(const float4*)(MEAN + (size_t)gr * FEATS + kc + c4 * 4);
            }
            sH[row][c4 * 4 + 0] = hv.x;
            sH[row][c4 * 4 + 1] = hv.y;
            sH[row][c4 * 4 + 2] = hv.z;
            sH[row][c4 * 4 + 3] = hv.w;
            sM[row][c4 * 4 + 0] = mv.x;
            sM[row][c4 * 4 + 1] = mv.y;
            sM[row][c4 * 4 + 2] = mv.z;
            sM[row][c4 * 4 + 3] = mv.w;
        }
#pragma unroll
        for (int i = 0; i < 4; ++i) {
            int idx = tid + i * 256;
            int row = idx >> 5;
            int c4  = idx & 31;
            *(float4*)&sW[row][c4 * 4] = *(const float4*)(Ws + (size_t)(kc + row) * FEATS + c4 * 4);
            *(float4*)&sV[row][c4 * 4] = *(const float4*)(Wn + (size_t)(kc + row) * FEATS + c4 * 4);
        }
        __syncthreads();

#pragma unroll
        for (int k = 0; k < KC; ++k) {
            float4 ws = *(const float4*)&sW[k][tx * 4];
            float4 wn = *(const float4*)&sV[k][tx * 4];
#pragma unroll
            for (int r = 0; r < 8; ++r) {
                float ah = sH[ty * 8 + r][k];
                float am = sM[ty * 8 + r][k];
                acc[r].x += ah * ws.x + am * wn.x;
                acc[r].y += ah * ws.y + am * wn.y;
                acc[r].z += ah * ws.z + am * wn.z;
                acc[r].w += ah * ws.w + am * wn.w;
            }
        }
        __syncthreads();
    }

    float4 bv = *(const float4*)(bias + tx * 4);
#pragma unroll
    for (int r = 0; r < 8; ++r) {
        int gr = rowBase + ty * 8 + r;
        if (gr >= nNodes) continue;
        float4 v;
        v.x = acc[r].x + bv.x;
        v.y = acc[r].y + bv.y;
        v.z = acc[r].z + bv.z;
        v.w = acc[r].w + bv.w;
        if (applyLrelu) {
            v.x = v.x > 0.f ? v.x : 0.2f * v.x;
            v.y = v.y > 0.f ? v.y : 0.2f * v.y;
            v.z = v.z > 0.f ? v.z : 0.2f * v.z;
            v.w = v.w > 0.f ? v.w : 0.2f * v.w;
        }
        *(float4*)(OUT + (size_t)gr * FEATS + tx * 4) = v;
    }
}

extern "C" void kernel_launch(void* const* d_in, const int* in_sizes, int n_in,
                              void* d_out, int out_size, void* d_ws, size_t ws_size,
                              hipStream_t stream) {
    const float* emb = (const float*)d_in[0];
    const float* W1s = (const float*)d_in[1];
    const float* W1n = (const float*)d_in[2];
    const float* b1  = (const float*)d_in[3];
    const float* W2s = (const float*)d_in[4];
    const float* W2n = (const float*)d_in[5];
    const float* b2  = (const float*)d_in[6];
    const int*   edg = (const int*)d_in[7];

    const int nE = in_sizes[7] / 2;
    const int* src = edg;
    const int* dst = edg + nE;

    const int nOff = N_NODES_C + 1;
    const int nBlocksScan = (nOff + SCAN_CHUNK - 1) / SCAN_CHUNK;  // 98

    // Workspace layout
    char* ws = (char*)d_ws;
    int*   cnt      = (int*)ws;                                  //  400 KB
    int*   off      = (int*)(ws + (512 << 10));                  //  ~400 KB
    int*   cursor   = (int*)(ws + (1024 << 10));                 //  400 KB
    int*   partials = (int*)(ws + (1536 << 10));                 //  4 KB
    int*   csr      = (int*)(ws + (1544 << 10));                 //  6.4 MB
    char*  big      = ws + (8 << 20);
    float* mean     = (float*)big;                               // 51.2 MB
    float* h1       = (float*)(big + (size_t)N_NODES_C * FEATS * sizeof(float));
    float* out      = (float*)d_out;

    // ---- CSR build (shared by both layers) ----
    hipMemsetAsync(cnt, 0, N_NODES_C * sizeof(int), stream);
    hist_kernel<<<(nE + 255) / 256, 256, 0, stream>>>(dst, cnt, nE);
    scanA_kernel<<<nBlocksScan, 256, 0, stream>>>(cnt, off, partials, nOff);
    scanB_kernel<<<1, 128, 0, stream>>>(partials, nBlocksScan);
    scanC_kernel<<<nBlocksScan, 256, 0, stream>>>(off, partials, nOff);
    copy_kernel<<<(N_NODES_C + 255) / 256, 256, 0, stream>>>(off, cursor, N_NODES_C);
    fill_kernel<<<(nE + 255) / 256, 256, 0, stream>>>(src, dst, cursor, csr, nE);

    const int gatherBlocks = (N_NODES_C + 1) / 2;
    const int gemmBlocks = (N_NODES_C + MT - 1) / MT;

    // ---- Layer 1 ----
    gather_mean<<<gatherBlocks, 256, 0, stream>>>(emb, csr, off, mean, N_NODES_C);
    sage_gemm<<<gemmBlocks, 256, 0, stream>>>(emb, mean, W1s, W1n, b1, h1, N_NODES_C, 1);

    // ---- Layer 2 ----
    gather_mean<<<gatherBlocks, 256, 0, stream>>>(h1, csr, off, mean, N_NODES_C);
    sage_gemm<<<gemmBlocks, 256, 0, stream>>>(h1, mean, W2s, W2n, b2, out, N_NODES_C, 0);
}

// Round 3
// 519.474 us; speedup vs baseline: 11.5171x; 1.8459x over previous
//
#include <hip/hip_runtime.h>
#include <hip/hip_bf16.h>

#define N_NODES_C 100000
#define FEATS 128
#define SCAN_CHUNK 1024   // 256 threads x 4 elements

typedef unsigned int uint32;
typedef __bf16 bf16_t;
typedef bf16_t bf16x8 __attribute__((ext_vector_type(8)));
typedef float f32x4 __attribute__((ext_vector_type(4)));

union Frag { uint4 u; bf16x8 v; };

__device__ __forceinline__ unsigned short f32_to_bf16_bits(float f) {
    uint32 u = __float_as_uint(f);
    u += 0x7fffu + ((u >> 16) & 1u);   // round-to-nearest-even (finite values)
    return (unsigned short)(u >> 16);
}
__device__ __forceinline__ float bf16_lo(uint32 p) { return __uint_as_float(p << 16); }
__device__ __forceinline__ float bf16_hi(uint32 p) { return __uint_as_float(p & 0xffff0000u); }

// ---------------- CSR build ----------------

__global__ void hist_kernel(const int* __restrict__ dst, int* __restrict__ cnt, int nE) {
    int i = blockIdx.x * blockDim.x + threadIdx.x;
    if (i < nE) atomicAdd(&cnt[dst[i]], 1);
}

__global__ __launch_bounds__(256) void scanA_kernel(const int* __restrict__ cnt,
                                                    int* __restrict__ off,
                                                    int* __restrict__ partials, int n) {
    __shared__ int ss[256];
    const int tid = threadIdx.x;
    const int base = blockIdx.x * SCAN_CHUNK;
    const int idx0 = base + tid * 4;
    int c[4];
#pragma unroll
    for (int i = 0; i < 4; ++i) {
        int gi = idx0 + i;
        c[i] = (gi < N_NODES_C) ? cnt[gi] : 0;
    }
    int s0 = c[0] + c[1] + c[2] + c[3];
    ss[tid] = s0;
    __syncthreads();
    for (int d = 1; d < 256; d <<= 1) {
        int t = (tid >= d) ? ss[tid - d] : 0;
        __syncthreads();
        ss[tid] += t;
        __syncthreads();
    }
    if (tid == 255) partials[blockIdx.x] = ss[255];
    int ex = ss[tid] - s0;
    int run = 0;
#pragma unroll
    for (int i = 0; i < 4; ++i) {
        int gi = idx0 + i;
        if (gi < n) off[gi] = ex + run;
        run += c[i];
    }
}

__global__ __launch_bounds__(128) void scanB_kernel(int* __restrict__ partials, int nP) {
    __shared__ int sp[128];
    const int tid = threadIdx.x;
    int orig = (tid < nP) ? partials[tid] : 0;
    sp[tid] = orig;
    __syncthreads();
    for (int d = 1; d < 128; d <<= 1) {
        int t = (tid >= d) ? sp[tid - d] : 0;
        __syncthreads();
        sp[tid] += t;
        __syncthreads();
    }
    if (tid < nP) partials[tid] = sp[tid] - orig;
}

__global__ __launch_bounds__(256) void scanC_kernel(int* __restrict__ off,
                                                    const int* __restrict__ partials, int n) {
    const int base = blockIdx.x * SCAN_CHUNK;
    const int add = partials[blockIdx.x];
    const int idx0 = base + threadIdx.x * 4;
#pragma unroll
    for (int i = 0; i < 4; ++i) {
        int gi = idx0 + i;
        if (gi < n) off[gi] += add;
    }
}

__global__ void copy_kernel(const int* __restrict__ a, int* __restrict__ b, int n) {
    int i = blockIdx.x * blockDim.x + threadIdx.x;
    if (i < n) b[i] = a[i];
}

__global__ void fill_kernel(const int* __restrict__ src, const int* __restrict__ dst,
                            int* __restrict__ cursor, int* __restrict__ csr, int nE) {
    int e = blockIdx.x * blockDim.x + threadIdx.x;
    if (e < nE) {
        int d = dst[e];
        int pos = atomicAdd(&cursor[d], 1);
        csr[pos] = src[e];
    }
}

// ---------------- fp32 -> bf16 cast (node table) ----------------
__global__ void cast_kernel(const float4* __restrict__ in, unsigned short* __restrict__ outp, int n4) {
    int i = blockIdx.x * blockDim.x + threadIdx.x;
    if (i >= n4) return;
    float4 v = in[i];
    union { unsigned short s[4]; uint2 u; } o;
    o.s[0] = f32_to_bf16_bits(v.x);
    o.s[1] = f32_to_bf16_bits(v.y);
    o.s[2] = f32_to_bf16_bits(v.z);
    o.s[3] = f32_to_bf16_bits(v.w);
    *(uint2*)(outp + (size_t)i * 4) = o.u;
}

// ---------------- weight pre-swizzle into B-fragment order ----------------
// wt layout: frag f = nt*8+ks (nt,ks in 0..7), lane l in 0..63, j in 0..7:
//   wt[(f*64+l)*8+j] = W[k][n],  n = nt*16+(l&15),  k = ks*32+(l>>4)*8+j
// where W = [Ws ; Wn] stacked along k (k<128 -> Ws, else Wn).
__global__ void wtprep_kernel(const float* __restrict__ Ws, const float* __restrict__ Wn,
                              unsigned short* __restrict__ wt) {
    int gid = blockIdx.x * 256 + threadIdx.x;   // 0..4095
    if (gid >= 4096) return;
    int frag = gid >> 6, lane = gid & 63;
    int nt = frag >> 3, ks = frag & 7;
    int n = nt * 16 + (lane & 15);
    int kbase = ks * 32 + (lane >> 4) * 8;
    union { unsigned short s[8]; uint4 u; } o;
#pragma unroll
    for (int j = 0; j < 8; ++j) {
        int k = kbase + j;
        float v = (k < 128) ? Ws[(size_t)k * FEATS + n] : Wn[(size_t)(k - 128) * FEATS + n];
        o.s[j] = f32_to_bf16_bits(v);
    }
    *(uint4*)(wt + (size_t)gid * 8) = o.u;
}

// ---------------- Gather (mean aggregation over bf16 table) ----------------
// 4 nodes per 256-thread block; one wave (64 lanes) per node, bf16x2 per lane.
__global__ __launch_bounds__(256) void gather_mean_bf16(const unsigned short* __restrict__ hb,
                                                        const int* __restrict__ csr,
                                                        const int* __restrict__ off,
                                                        unsigned short* __restrict__ meanb,
                                                        int nNodes) {
    const int node = blockIdx.x * 4 + (threadIdx.x >> 6);
    const int lane = threadIdx.x & 63;
    if (node >= nNodes) return;
    const int start = off[node];
    const int end = off[node + 1];
    const uint32* h32 = (const uint32*)hb;   // row = 64 uints
    float a0 = 0.f, a1 = 0.f;
    int e = start;
    for (; e + 8 <= end; e += 8) {
        int s[8];
#pragma unroll
        for (int j = 0; j < 8; ++j) s[j] = csr[e + j];
        uint32 u[8];
#pragma unroll
        for (int j = 0; j < 8; ++j) u[j] = h32[(size_t)s[j] * 64 + lane];
#pragma unroll
        for (int j = 0; j < 8; ++j) { a0 += bf16_lo(u[j]); a1 += bf16_hi(u[j]); }
    }
    for (; e < end; ++e) {
        uint32 u = h32[(size_t)csr[e] * 64 + lane];
        a0 += bf16_lo(u); a1 += bf16_hi(u);
    }
    const int deg = end - start;
    const float invd = (deg > 0) ? (1.f / (float)deg) : 0.f;
    uint32 o = ((uint32)f32_to_bf16_bits(a1 * invd) << 16) | (uint32)f32_to_bf16_bits(a0 * invd);
    ((uint32*)meanb)[(size_t)node * 64 + lane] = o;
}

// ---------------- MFMA SAGE GEMM (LDS-free) ----------------
// Per wave: 16-row stripe x 128 cols, K=256 = [HB | MB].
// A-frag: natural 16B row chunks. B-frag: pre-swizzled wt, coalesced 16B loads.
// mode 1: +bias, leaky-relu(0.2), write bf16. mode 0: +bias, write fp32.
__global__ __launch_bounds__(256) void sage_gemm_mfma(const unsigned short* __restrict__ HB,
                                                      const unsigned short* __restrict__ MB,
                                                      const unsigned short* __restrict__ WT,
                                                      const float* __restrict__ bias,
                                                      void* __restrict__ OUTP,
                                                      int nNodes, int mode) {
    const int wave = threadIdx.x >> 6;
    const int lane = threadIdx.x & 63;
    const int waveBase = blockIdx.x * 64 + wave * 16;
    const int m = lane & 15;
    const int quad = lane >> 4;

    int arow = waveBase + m;
    if (arow >= nNodes) arow = nNodes - 1;           // clamp loads; stores guarded below
    const uint4* hrow = (const uint4*)(HB + (size_t)arow * FEATS);   // 16 x uint4 per row
    const uint4* mrow = (const uint4*)(MB + (size_t)arow * FEATS);

    Frag a[8];
#pragma unroll
    for (int ks = 0; ks < 4; ++ks) a[ks].u = hrow[ks * 4 + quad];
#pragma unroll
    for (int ks = 0; ks < 4; ++ks) a[ks + 4].u = mrow[ks * 4 + quad];

    const uint4* wt4 = (const uint4*)WT;
    f32x4 acc[8];
#pragma unroll
    for (int nt = 0; nt < 8; ++nt) acc[nt] = (f32x4){0.f, 0.f, 0.f, 0.f};

#pragma unroll
    for (int ks = 0; ks < 8; ++ks) {
#pragma unroll
        for (int nt = 0; nt < 8; ++nt) {
            Frag b;
            b.u = wt4[(size_t)(nt * 8 + ks) * 64 + lane];
            acc[nt] = __builtin_amdgcn_mfma_f32_16x16x32_bf16(a[ks].v, b.v, acc[nt], 0, 0, 0);
        }
    }

#pragma unroll
    for (int nt = 0; nt < 8; ++nt) {
        const int col = nt * 16 + m;
        const float bv = bias[col];
#pragma unroll
        for (int r = 0; r < 4; ++r) {
            const int grow = waveBase + quad * 4 + r;   // C/D: row=(lane>>4)*4+reg, col=lane&15
            if (grow >= nNodes) continue;
            float v = acc[nt][r] + bv;
            if (mode) {
                v = v > 0.f ? v : 0.2f * v;
                ((unsigned short*)OUTP)[(size_t)grow * FEATS + col] = f32_to_bf16_bits(v);
            } else {
                ((float*)OUTP)[(size_t)grow * FEATS + col] = v;
            }
        }
    }
}

extern "C" void kernel_launch(void* const* d_in, const int* in_sizes, int n_in,
                              void* d_out, int out_size, void* d_ws, size_t ws_size,
                              hipStream_t stream) {
    const float* emb = (const float*)d_in[0];
    const float* W1s = (const float*)d_in[1];
    const float* W1n = (const float*)d_in[2];
    const float* b1  = (const float*)d_in[3];
    const float* W2s = (const float*)d_in[4];
    const float* W2n = (const float*)d_in[5];
    const float* b2  = (const float*)d_in[6];
    const int*   edg = (const int*)d_in[7];

    const int nE = in_sizes[7] / 2;
    const int* src = edg;
    const int* dst = edg + nE;

    const int nOff = N_NODES_C + 1;
    const int nBlocksScan = (nOff + SCAN_CHUNK - 1) / SCAN_CHUNK;  // 98

    const size_t bfTab = (size_t)N_NODES_C * FEATS * sizeof(unsigned short);  // 25.6 MB

    char* ws = (char*)d_ws;
    int* cnt      = (int*)(ws);
    int* off      = (int*)(ws + (512 << 10));
    int* cursor   = (int*)(ws + (1024 << 10));
    int* partials = (int*)(ws + (1536 << 10));
    int* csr      = (int*)(ws + (1544 << 10));                 // 6.4 MB
    unsigned short* wt1 = (unsigned short*)(ws + (8 << 20));   // 64 KB
    unsigned short* wt2 = (unsigned short*)(ws + (8 << 20) + (64 << 10));
    unsigned short* hb0 = (unsigned short*)(ws + (8 << 20) + (128 << 10));
    unsigned short* h1b = (unsigned short*)((char*)hb0 + bfTab);
    unsigned short* mnb = (unsigned short*)((char*)h1b + bfTab);
    float* out = (float*)d_out;

    // ---- CSR build ----
    hipMemsetAsync(cnt, 0, N_NODES_C * sizeof(int), stream);
    hist_kernel<<<(nE + 255) / 256, 256, 0, stream>>>(dst, cnt, nE);
    scanA_kernel<<<nBlocksScan, 256, 0, stream>>>(cnt, off, partials, nOff);
    scanB_kernel<<<1, 128, 0, stream>>>(partials, nBlocksScan);
    scanC_kernel<<<nBlocksScan, 256, 0, stream>>>(off, partials, nOff);
    copy_kernel<<<(N_NODES_C + 255) / 256, 256, 0, stream>>>(off, cursor, N_NODES_C);
    fill_kernel<<<(nE + 255) / 256, 256, 0, stream>>>(src, dst, cursor, csr, nE);

    // ---- Precompute bf16 node table + swizzled weights ----
    const int n4 = N_NODES_C * FEATS / 4;   // 3.2M
    cast_kernel<<<(n4 + 255) / 256, 256, 0, stream>>>((const float4*)emb, hb0, n4);
    wtprep_kernel<<<16, 256, 0, stream>>>(W1s, W1n, wt1);
    wtprep_kernel<<<16, 256, 0, stream>>>(W2s, W2n, wt2);

    const int gatherBlocks = (N_NODES_C + 3) / 4;
    const int gemmBlocks = (N_NODES_C + 63) / 64;

    // ---- Layer 1 ----
    gather_mean_bf16<<<gatherBlocks, 256, 0, stream>>>(hb0, csr, off, mnb, N_NODES_C);
    sage_gemm_mfma<<<gemmBlocks, 256, 0, stream>>>(hb0, mnb, wt1, b1, h1b, N_NODES_C, 1);

    // ---- Layer 2 ----
    gather_mean_bf16<<<gatherBlocks, 256, 0, stream>>>(h1b, csr, off, mnb, N_NODES_C);
    sage_gemm_mfma<<<gemmBlocks, 256, 0, stream>>>(h1b, mnb, wt2, b2, out, N_NODES_C, 0);
}

// Round 4
// 390.094 us; speedup vs baseline: 15.3370x; 1.3317x over previous
//
#include <hip/hip_runtime.h>
#include <hip/hip_bf16.h>

#define N_NODES_C 100000
#define FEATS 128
#define SCAN_CHUNK 1024   // 256 threads x 4 elements
#define SH 10             // bucket shift: 1024 nodes per bucket
#define NBK 128           // padded bucket count (active: 98)
#define PB  256           // partition blocks

typedef unsigned int uint32;
typedef __bf16 bf16_t;
typedef bf16_t bf16x8 __attribute__((ext_vector_type(8)));
typedef float f32x4 __attribute__((ext_vector_type(4)));

union Frag { uint4 u; bf16x8 v; };

__device__ __forceinline__ unsigned short f32_to_bf16_bits(float f) {
    uint32 u = __float_as_uint(f);
    u += 0x7fffu + ((u >> 16) & 1u);   // round-to-nearest-even (finite values)
    return (unsigned short)(u >> 16);
}
__device__ __forceinline__ float bf16_lo(uint32 p) { return __uint_as_float(p << 16); }
__device__ __forceinline__ float bf16_hi(uint32 p) { return __uint_as_float(p & 0xffff0000u); }

// ---------------- CSR build: bucket partition ----------------

// P1: per-block bucket histogram (bucket-major output: gHist[bucket*PB + block])
__global__ __launch_bounds__(256) void part_count(const int* __restrict__ dst,
                                                  int* __restrict__ gHist,
                                                  int nE, int chunk) {
    __shared__ int h[NBK];
    const int tid = threadIdx.x;
    if (tid < NBK) h[tid] = 0;
    __syncthreads();
    const int b0 = blockIdx.x * chunk;
    const int e1 = min(b0 + chunk, nE);
    for (int e = b0 + tid; e < e1; e += 256)
        atomicAdd(&h[dst[e] >> SH], 1);
    __syncthreads();
    if (tid < NBK) gHist[tid * gridDim.x + blockIdx.x] = h[tid];
}

// Generic 3-phase exclusive scan (in -> out, length nIn)
__global__ __launch_bounds__(256) void scanA_kernel(const int* __restrict__ in,
                                                    int* __restrict__ out,
                                                    int* __restrict__ partials, int nIn) {
    __shared__ int ss[256];
    const int tid = threadIdx.x;
    const int base = blockIdx.x * SCAN_CHUNK;
    const int idx0 = base + tid * 4;
    int c[4];
#pragma unroll
    for (int i = 0; i < 4; ++i) {
        int gi = idx0 + i;
        c[i] = (gi < nIn) ? in[gi] : 0;
    }
    int s0 = c[0] + c[1] + c[2] + c[3];
    ss[tid] = s0;
    __syncthreads();
    for (int d = 1; d < 256; d <<= 1) {
        int t = (tid >= d) ? ss[tid - d] : 0;
        __syncthreads();
        ss[tid] += t;
        __syncthreads();
    }
    if (tid == 255) partials[blockIdx.x] = ss[255];
    int ex = ss[tid] - s0;
    int run = 0;
#pragma unroll
    for (int i = 0; i < 4; ++i) {
        int gi = idx0 + i;
        if (gi < nIn) out[gi] = ex + run;
        run += c[i];
    }
}

__global__ __launch_bounds__(128) void scanB_kernel(int* __restrict__ partials, int nP) {
    __shared__ int sp[128];
    const int tid = threadIdx.x;
    int orig = (tid < nP) ? partials[tid] : 0;
    sp[tid] = orig;
    __syncthreads();
    for (int d = 1; d < 128; d <<= 1) {
        int t = (tid >= d) ? sp[tid - d] : 0;
        __syncthreads();
        sp[tid] += t;
        __syncthreads();
    }
    if (tid < nP) partials[tid] = sp[tid] - orig;
}

__global__ __launch_bounds__(256) void scanC_kernel(int* __restrict__ out,
                                                    const int* __restrict__ partials, int nIn) {
    const int base = blockIdx.x * SCAN_CHUNK;
    const int add = partials[blockIdx.x];
    const int idx0 = base + threadIdx.x * 4;
#pragma unroll
    for (int i = 0; i < 4; ++i) {
        int gi = idx0 + i;
        if (gi < nIn) out[gi] += add;
    }
}

// P2: scatter (src,dst) into bucket-partitioned ebuf; each block writes dense
// reserved sub-regions (coalesced-ish, L2-resident)
__global__ __launch_bounds__(256) void part_scatter(const int* __restrict__ src,
                                                    const int* __restrict__ dst,
                                                    const int* __restrict__ gScan,
                                                    int2* __restrict__ ebuf,
                                                    int nE, int chunk) {
    __shared__ int cur[NBK];
    const int tid = threadIdx.x;
    if (tid < NBK) cur[tid] = gScan[tid * gridDim.x + blockIdx.x];
    __syncthreads();
    const int b0 = blockIdx.x * chunk;
    const int e1 = min(b0 + chunk, nE);
    for (int e = b0 + tid; e < e1; e += 256) {
        int d = dst[e];
        int pos = atomicAdd(&cur[d >> SH], 1);
        ebuf[pos] = make_int2(src[e], d);
    }
}

// P3: per-bucket CSR finalize — LDS histogram + scan, writes off[] and csr[]
// within an L2-resident window.
__global__ __launch_bounds__(1024) void bucket_csr(const int2* __restrict__ ebuf,
                                                   const int* __restrict__ gScan,
                                                   int* __restrict__ off,
                                                   int* __restrict__ csr,
                                                   int nE, int nPB) {
    __shared__ int cnt[1 << SH];
    __shared__ int ss[1 << SH];
    const int b = blockIdx.x;
    const int tid = threadIdx.x;
    const int start = gScan[b * nPB];
    const int end = gScan[(b + 1) * nPB];   // b+1 < NBK always (active buckets < 128)
    const int nodeBase = b << SH;
    cnt[tid] = 0;
    __syncthreads();
    for (int e = start + tid; e < end; e += 1024)
        atomicAdd(&cnt[ebuf[e].y - nodeBase], 1);
    __syncthreads();
    int own = cnt[tid];
    ss[tid] = own;
    __syncthreads();
    for (int d = 1; d < 1024; d <<= 1) {
        int t = (tid >= d) ? ss[tid - d] : 0;
        __syncthreads();
        ss[tid] += t;
        __syncthreads();
    }
    int ex = ss[tid] - own;
    cnt[tid] = ex;                     // becomes placement cursor
    int node = nodeBase + tid;
    if (node < N_NODES_C) off[node] = start + ex;
    if (b == gridDim.x - 1 && tid == 0) off[N_NODES_C] = nE;
    __syncthreads();
    for (int e = start + tid; e < end; e += 1024) {
        int2 ed = ebuf[e];
        int pos = atomicAdd(&cnt[ed.y - nodeBase], 1);
        csr[start + pos] = ed.x;
    }
}

// ---------------- fp32 -> bf16 cast (node table) ----------------
__global__ void cast_kernel(const float4* __restrict__ in, unsigned short* __restrict__ outp, int n4) {
    int i = blockIdx.x * blockDim.x + threadIdx.x;
    if (i >= n4) return;
    float4 v = in[i];
    union { unsigned short s[4]; uint2 u; } o;
    o.s[0] = f32_to_bf16_bits(v.x);
    o.s[1] = f32_to_bf16_bits(v.y);
    o.s[2] = f32_to_bf16_bits(v.z);
    o.s[3] = f32_to_bf16_bits(v.w);
    *(uint2*)(outp + (size_t)i * 4) = o.u;
}

// ---------------- weight pre-swizzle into B-fragment order ----------------
// wt[(f*64+l)*8+j] = W[k][n], f=nt*8+ks, n=nt*16+(l&15), k=ks*32+(l>>4)*8+j
// W = [Ws ; Wn] stacked along k (k<128 -> Ws, else Wn).
__global__ void wtprep_kernel(const float* __restrict__ Ws, const float* __restrict__ Wn,
                              unsigned short* __restrict__ wt) {
    int gid = blockIdx.x * 256 + threadIdx.x;   // 0..4095
    if (gid >= 4096) return;
    int frag = gid >> 6, lane = gid & 63;
    int nt = frag >> 3, ks = frag & 7;
    int n = nt * 16 + (lane & 15);
    int kbase = ks * 32 + (lane >> 4) * 8;
    union { unsigned short s[8]; uint4 u; } o;
#pragma unroll
    for (int j = 0; j < 8; ++j) {
        int k = kbase + j;
        float v = (k < 128) ? Ws[(size_t)k * FEATS + n] : Wn[(size_t)(k - 128) * FEATS + n];
        o.s[j] = f32_to_bf16_bits(v);
    }
    *(uint4*)(wt + (size_t)gid * 8) = o.u;
}

// ---------------- Gather (mean aggregation over bf16 table) ----------------
// 4 nodes per 256-thread block; one wave per node, bf16x2 per lane.
__global__ __launch_bounds__(256) void gather_mean_bf16(const unsigned short* __restrict__ hb,
                                                        const int* __restrict__ csr,
                                                        const int* __restrict__ off,
                                                        unsigned short* __restrict__ meanb,
                                                        int nNodes) {
    const int node = blockIdx.x * 4 + (threadIdx.x >> 6);
    const int lane = threadIdx.x & 63;
    if (node >= nNodes) return;
    const int start = off[node];
    const int end = off[node + 1];
    const uint32* h32 = (const uint32*)hb;   // row = 64 uints
    float a0 = 0.f, a1 = 0.f;
    int e = start;
    for (; e + 8 <= end; e += 8) {
        int s[8];
#pragma unroll
        for (int j = 0; j < 8; ++j) s[j] = csr[e + j];
        uint32 u[8];
#pragma unroll
        for (int j = 0; j < 8; ++j) u[j] = h32[(size_t)s[j] * 64 + lane];
#pragma unroll
        for (int j = 0; j < 8; ++j) { a0 += bf16_lo(u[j]); a1 += bf16_hi(u[j]); }
    }
    for (; e < end; ++e) {
        uint32 u = h32[(size_t)csr[e] * 64 + lane];
        a0 += bf16_lo(u); a1 += bf16_hi(u);
    }
    const int deg = end - start;
    const float invd = (deg > 0) ? (1.f / (float)deg) : 0.f;
    uint32 o = ((uint32)f32_to_bf16_bits(a1 * invd) << 16) | (uint32)f32_to_bf16_bits(a0 * invd);
    ((uint32*)meanb)[(size_t)node * 64 + lane] = o;
}

// ---------------- MFMA SAGE GEMM (LDS-free) ----------------
__global__ __launch_bounds__(256) void sage_gemm_mfma(const unsigned short* __restrict__ HB,
                                                      const unsigned short* __restrict__ MB,
                                                      const unsigned short* __restrict__ WT,
                                                      const float* __restrict__ bias,
                                                      void* __restrict__ OUTP,
                                                      int nNodes, int mode) {
    const int wave = threadIdx.x >> 6;
    const int lane = threadIdx.x & 63;
    const int waveBase = blockIdx.x * 64 + wave * 16;
    const int m = lane & 15;
    const int quad = lane >> 4;

    int arow = waveBase + m;
    if (arow >= nNodes) arow = nNodes - 1;           // clamp loads; stores guarded below
    const uint4* hrow = (const uint4*)(HB + (size_t)arow * FEATS);
    const uint4* mrow = (const uint4*)(MB + (size_t)arow * FEATS);

    Frag a[8];
#pragma unroll
    for (int ks = 0; ks < 4; ++ks) a[ks].u = hrow[ks * 4 + quad];
#pragma unroll
    for (int ks = 0; ks < 4; ++ks) a[ks + 4].u = mrow[ks * 4 + quad];

    const uint4* wt4 = (const uint4*)WT;
    f32x4 acc[8];
#pragma unroll
    for (int nt = 0; nt < 8; ++nt) acc[nt] = (f32x4){0.f, 0.f, 0.f, 0.f};

#pragma unroll
    for (int ks = 0; ks < 8; ++ks) {
#pragma unroll
        for (int nt = 0; nt < 8; ++nt) {
            Frag b;
            b.u = wt4[(size_t)(nt * 8 + ks) * 64 + lane];
            acc[nt] = __builtin_amdgcn_mfma_f32_16x16x32_bf16(a[ks].v, b.v, acc[nt], 0, 0, 0);
        }
    }

#pragma unroll
    for (int nt = 0; nt < 8; ++nt) {
        const int col = nt * 16 + m;
        const float bv = bias[col];
#pragma unroll
        for (int r = 0; r < 4; ++r) {
            const int grow = waveBase + quad * 4 + r;   // C/D: row=(lane>>4)*4+reg, col=lane&15
            if (grow >= nNodes) continue;
            float v = acc[nt][r] + bv;
            if (mode) {
                v = v > 0.f ? v : 0.2f * v;
                ((unsigned short*)OUTP)[(size_t)grow * FEATS + col] = f32_to_bf16_bits(v);
            } else {
                ((float*)OUTP)[(size_t)grow * FEATS + col] = v;
            }
        }
    }
}

extern "C" void kernel_launch(void* const* d_in, const int* in_sizes, int n_in,
                              void* d_out, int out_size, void* d_ws, size_t ws_size,
                              hipStream_t stream) {
    const float* emb = (const float*)d_in[0];
    const float* W1s = (const float*)d_in[1];
    const float* W1n = (const float*)d_in[2];
    const float* b1  = (const float*)d_in[3];
    const float* W2s = (const float*)d_in[4];
    const float* W2n = (const float*)d_in[5];
    const float* b2  = (const float*)d_in[6];
    const int*   edg = (const int*)d_in[7];

    const int nE = in_sizes[7] / 2;
    const int* src = edg;
    const int* dst = edg + nE;

    const size_t bfTab = (size_t)N_NODES_C * FEATS * sizeof(unsigned short);  // 25.6 MB
    const int nHist = NBK * PB;                      // 32768
    const int nScanBlocks = (nHist + SCAN_CHUNK - 1) / SCAN_CHUNK;  // 32
    const int chunk = (nE + PB - 1) / PB;            // 6250
    const int nActB = (N_NODES_C + (1 << SH) - 1) >> SH;            // 98

    char* ws = (char*)d_ws;
    int* off      = (int*)(ws);                      // 400 KB + 4
    int* gHist    = (int*)(ws + (512 << 10));        // 128 KB
    int* partials = (int*)(ws + (768 << 10));        // tiny
    int* csr      = (int*)(ws + (1 << 20));          // 6.4 MB
    int2* ebuf    = (int2*)(ws + (8 << 20));         // 12.8 MB
    unsigned short* wt1 = (unsigned short*)(ws + (21 << 20));   // 64 KB
    unsigned short* wt2 = (unsigned short*)(ws + (21 << 20) + (64 << 10));
    unsigned short* hb0 = (unsigned short*)(ws + (22 << 20));
    unsigned short* h1b = (unsigned short*)((char*)hb0 + bfTab);
    unsigned short* mnb = (unsigned short*)((char*)h1b + bfTab);
    float* out = (float*)d_out;

    // ---- CSR build via bucket partition ----
    part_count<<<PB, 256, 0, stream>>>(dst, gHist, nE, chunk);
    scanA_kernel<<<nScanBlocks, 256, 0, stream>>>(gHist, gHist, partials, nHist);
    scanB_kernel<<<1, 128, 0, stream>>>(partials, nScanBlocks);
    scanC_kernel<<<nScanBlocks, 256, 0, stream>>>(gHist, partials, nHist);
    part_scatter<<<PB, 256, 0, stream>>>(src, dst, gHist, ebuf, nE, chunk);
    bucket_csr<<<nActB, 1024, 0, stream>>>(ebuf, gHist, off, csr, nE, PB);

    // ---- Precompute bf16 node table + swizzled weights ----
    const int n4 = N_NODES_C * FEATS / 4;   // 3.2M
    cast_kernel<<<(n4 + 255) / 256, 256, 0, stream>>>((const float4*)emb, hb0, n4);
    wtprep_kernel<<<16, 256, 0, stream>>>(W1s, W1n, wt1);
    wtprep_kernel<<<16, 256, 0, stream>>>(W2s, W2n, wt2);

    const int gatherBlocks = (N_NODES_C + 3) / 4;
    const int gemmBlocks = (N_NODES_C + 63) / 64;

    // ---- Layer 1 ----
    gather_mean_bf16<<<gatherBlocks, 256, 0, stream>>>(hb0, csr, off, mnb, N_NODES_C);
    sage_gemm_mfma<<<gemmBlocks, 256, 0, stream>>>(hb0, mnb, wt1, b1, h1b, N_NODES_C, 1);

    // ---- Layer 2 ----
    gather_mean_bf16<<<gatherBlocks, 256, 0, stream>>>(h1b, csr, off, mnb, N_NODES_C);
    sage_gemm_mfma<<<gemmBlocks, 256, 0, stream>>>(h1b, mnb, wt2, b2, out, N_NODES_C, 0);
}